// Round 3
// baseline (1088.860 us; speedup 1.0000x reference)
//
#include <hip/hip_runtime.h>

#define BB 32
#define CC 512
#define KK 128
#define HW 16384  // 128*128

typedef float f32x4 __attribute__((ext_vector_type(4)));

// ---------------------------------------------------------------------------
// Fused pass 1+2: per-(b,c) channel abs-max, then the LAST block to finish
// within each batch sorts that batch's 512 scores (bitonic, 256 thr × 2 elem)
// and writes topk_idx + softmax weights. Last-block detection via per-batch
// acq_rel atomic counter (reset by hipMemsetAsync each launch).
// ---------------------------------------------------------------------------
__global__ __launch_bounds__(256) void scores_topk_kernel(
        const float* __restrict__ x,
        float* __restrict__ scores,
        int* __restrict__ topk_idx,
        float* __restrict__ wout,
        unsigned int* __restrict__ cnt) {
    const int ch = blockIdx.x;   // b*CC + c
    const int b  = ch >> 9;      // CC = 512
    const int tid = threadIdx.x;

    // ---- abs-max over this channel (nontemporal stream) ----
    const f32x4* p = reinterpret_cast<const f32x4*>(x) + (size_t)ch * (HW / 4);
    float m = 0.0f;
#pragma unroll
    for (int i = 0; i < 16; ++i) {
        f32x4 v = __builtin_nontemporal_load(&p[tid + i * 256]);
        m = fmaxf(m, fmaxf(fmaxf(fabsf(v.x), fabsf(v.y)),
                           fmaxf(fabsf(v.z), fabsf(v.w))));
    }
#pragma unroll
    for (int off = 32; off > 0; off >>= 1)
        m = fmaxf(m, __shfl_down(m, off, 64));

    __shared__ float smax[4];
    __shared__ bool  last;
    const int wave = tid >> 6;
    if ((tid & 63) == 0) smax[wave] = m;
    __syncthreads();
    if (tid == 0) {
        const float bm = fmaxf(fmaxf(smax[0], smax[1]), fmaxf(smax[2], smax[3]));
        // agent-scope store (bypasses non-coherent L1/L2), ordered before the
        // release half of the acq_rel RMW below
        __hip_atomic_store(&scores[ch], bm, __ATOMIC_RELAXED,
                           __HIP_MEMORY_SCOPE_AGENT);
        const unsigned old = __hip_atomic_fetch_add(&cnt[b], 1u,
                                                    __ATOMIC_ACQ_REL,
                                                    __HIP_MEMORY_SCOPE_AGENT);
        last = (old == CC - 1);
    }
    __syncthreads();
    if (!last) return;

    // ---- this block saw all 512 scores of batch b: sort + weights ----
    __shared__ float s[CC];
    __shared__ int   idx[CC];
    __shared__ float red[2];

#pragma unroll
    for (int h = 0; h < 2; ++h) {
        const int c = tid + h * 256;
        s[c] = __hip_atomic_load(&scores[b * CC + c], __ATOMIC_RELAXED,
                                 __HIP_MEMORY_SCOPE_AGENT);
        idx[c] = c;
    }
    __syncthreads();

    // bitonic sort: descending by score, ties -> ascending index (lax.top_k)
    for (int k = 2; k <= CC; k <<= 1) {
        for (int j = k >> 1; j > 0; j >>= 1) {
            const int i   = 2 * tid - (tid & (j - 1));
            const int ixj = i + j;
            float sa = s[i], sb = s[ixj];
            int   ia = idx[i], ib = idx[ixj];
            const bool a_first  = (sa > sb) || (sa == sb && ia < ib);
            const bool desc_seg = ((i & k) == 0);
            if (desc_seg ? !a_first : a_first) {
                s[i] = sb;  s[ixj] = sa;
                idx[i] = ib; idx[ixj] = ia;
            }
            __syncthreads();
        }
    }

    // softmax weights over top-K (Z cancels under normalization)
    const float smaxv = s[0];
    if (tid < KK) {
        const float e = expf(s[tid] - smaxv);
        float esum = e;
#pragma unroll
        for (int off = 32; off > 0; off >>= 1)
            esum += __shfl_down(esum, off, 64);
        if ((tid & 63) == 0) red[tid >> 6] = esum;
    }
    __syncthreads();
    if (tid < KK) {
        const float total = fmaxf(red[0] + red[1], 1e-12f);
        const float e = expf(s[tid] - smaxv);
        topk_idx[b * KK + tid] = idx[tid];
        wout[b * KK + tid] = e / total;
    }
}

// ---------------------------------------------------------------------------
// Pass 3: gather selected channels scaled by weight. One 256-thread block
// per (b,k). Register-staged loads, nontemporal stores.
// ---------------------------------------------------------------------------
__global__ __launch_bounds__(256) void gather_kernel(const float* __restrict__ x,
                                                     const int* __restrict__ topk_idx,
                                                     const float* __restrict__ w,
                                                     float* __restrict__ out) {
    const int bk = blockIdx.x;  // b*KK + k
    const int b = bk >> 7;
    const int c = topk_idx[bk];
    const float wv = w[bk];

    const f32x4* src = reinterpret_cast<const f32x4*>(x) +
                       ((size_t)(b * CC + c)) * (HW / 4);
    f32x4* dst = reinterpret_cast<f32x4*>(out) + (size_t)bk * (HW / 4);
    const int tid = threadIdx.x;

    f32x4 r[16];
#pragma unroll
    for (int i = 0; i < 16; ++i)
        r[i] = src[tid + i * 256];
#pragma unroll
    for (int i = 0; i < 16; ++i) {
        f32x4 v = r[i];
        v.x *= wv; v.y *= wv; v.z *= wv; v.w *= wv;
        __builtin_nontemporal_store(v, &dst[tid + i * 256]);
    }
}

extern "C" void kernel_launch(void* const* d_in, const int* in_sizes, int n_in,
                              void* d_out, int out_size, void* d_ws, size_t ws_size,
                              hipStream_t stream) {
    const float* x = (const float*)d_in[0];
    float* out = (float*)d_out;

    char* ws = (char*)d_ws;
    float* scores = (float*)ws;                         ws += BB * CC * sizeof(float);
    int* idx = (int*)ws;                                ws += BB * KK * sizeof(int);
    float* w = (float*)ws;                              ws += BB * KK * sizeof(float);
    unsigned int* cnt = (unsigned int*)ws;              // BB counters

    hipMemsetAsync(cnt, 0, BB * sizeof(unsigned int), stream);
    scores_topk_kernel<<<BB * CC, 256, 0, stream>>>(x, scores, idx, w, cnt);
    gather_kernel<<<BB * KK, 256, 0, stream>>>(x, idx, w, out);
}

// Round 4
// 289.228 us; speedup vs baseline: 3.7647x; 3.7647x over previous
//
#include <hip/hip_runtime.h>

#define BB 32
#define CC 512
#define KK 128
#define HW 16384  // 128*128

typedef float f32x4 __attribute__((ext_vector_type(4)));

// ---------------------------------------------------------------------------
// Pass 1: per-(b,c) channel abs-max. One 256-thread block per channel.
// Cacheable loads (no nt): the ~256 MB tail of x stays resident in the
// memory-side Infinity Cache for pass 3 to hit.
// ---------------------------------------------------------------------------
__global__ __launch_bounds__(256) void scores_kernel(const float* __restrict__ x,
                                                     float* __restrict__ scores) {
    const int ch = blockIdx.x;  // b*CC + c
    const f32x4* p = reinterpret_cast<const f32x4*>(x) + (size_t)ch * (HW / 4);
    const int tid = threadIdx.x;

    float m = 0.0f;
#pragma unroll
    for (int i = 0; i < 16; ++i) {
        f32x4 v = p[tid + i * 256];
        m = fmaxf(m, fmaxf(fmaxf(fabsf(v.x), fabsf(v.y)),
                           fmaxf(fabsf(v.z), fabsf(v.w))));
    }
    // wave (64-lane) reduction
#pragma unroll
    for (int off = 32; off > 0; off >>= 1)
        m = fmaxf(m, __shfl_down(m, off, 64));

    __shared__ float smax[4];
    const int wave = tid >> 6;
    if ((tid & 63) == 0) smax[wave] = m;
    __syncthreads();
    if (tid == 0)
        scores[ch] = fmaxf(fmaxf(smax[0], smax[1]), fmaxf(smax[2], smax[3]));
}

// ---------------------------------------------------------------------------
// Pass 2: per-batch top-K + softmax weights. One 512-thread block per batch.
// Bitonic sort (score desc, idx asc) — strict total order, matches
// jax.lax.top_k. Softmax Z cancels under normalization.
// ---------------------------------------------------------------------------
__global__ __launch_bounds__(512) void topk_kernel(const float* __restrict__ scores,
                                                   int* __restrict__ topk_idx,
                                                   float* __restrict__ wout) {
    const int b = blockIdx.x;
    const int tid = threadIdx.x;  // 0..511

    __shared__ float s[CC];
    __shared__ int idx[CC];
    __shared__ float red[8];

    s[tid] = scores[b * CC + tid];
    idx[tid] = tid;
    __syncthreads();

    for (int k = 2; k <= CC; k <<= 1) {
        for (int j = k >> 1; j > 0; j >>= 1) {
            const int ixj = tid ^ j;
            if (ixj > tid) {
                float sa = s[tid], sb = s[ixj];
                int ia = idx[tid], ib = idx[ixj];
                const bool a_first = (sa > sb) || (sa == sb && ia < ib);
                const bool desc_seg = ((tid & k) == 0);
                const bool do_swap = desc_seg ? !a_first : a_first;
                if (do_swap) {
                    s[tid] = sb; s[ixj] = sa;
                    idx[tid] = ib; idx[ixj] = ia;
                }
            }
            __syncthreads();
        }
    }

    const float smaxv = s[0];
    float e = (tid < KK) ? expf(s[tid] - smaxv) : 0.0f;

    float esum = e;
#pragma unroll
    for (int off = 32; off > 0; off >>= 1)
        esum += __shfl_down(esum, off, 64);
    const int wave = tid >> 6;
    if ((tid & 63) == 0) red[wave] = esum;
    __syncthreads();
    if (tid < KK) {
        float total = 0.0f;
#pragma unroll
        for (int wv = 0; wv < 8; ++wv) total += red[wv];
        total = fmaxf(total, 1e-12f);
        topk_idx[b * KK + tid] = idx[tid];
        wout[b * KK + tid] = e / total;
    }
}

// ---------------------------------------------------------------------------
// Pass 3: gather selected channels scaled by weight. One 256-thread block
// per (b,k), REVERSED dispatch order: high-b batches (whose source data is
// still resident in the L3 tail from pass 1) run first, before gather's own
// traffic churns the cache. Register-staged loads, nontemporal stores
// (output is never re-read).
// ---------------------------------------------------------------------------
__global__ __launch_bounds__(256) void gather_kernel(const float* __restrict__ x,
                                                     const int* __restrict__ topk_idx,
                                                     const float* __restrict__ w,
                                                     float* __restrict__ out) {
    const int bk = (BB * KK - 1) - blockIdx.x;  // reversed: b=31 first
    const int b = bk >> 7;
    const int c = topk_idx[bk];
    const float wv = w[bk];

    const f32x4* src = reinterpret_cast<const f32x4*>(x) +
                       ((size_t)(b * CC + c)) * (HW / 4);
    f32x4* dst = reinterpret_cast<f32x4*>(out) + (size_t)bk * (HW / 4);
    const int tid = threadIdx.x;

    f32x4 r[16];
#pragma unroll
    for (int i = 0; i < 16; ++i)
        r[i] = src[tid + i * 256];
#pragma unroll
    for (int i = 0; i < 16; ++i) {
        f32x4 v = r[i];
        v.x *= wv; v.y *= wv; v.z *= wv; v.w *= wv;
        __builtin_nontemporal_store(v, &dst[tid + i * 256]);
    }
}

extern "C" void kernel_launch(void* const* d_in, const int* in_sizes, int n_in,
                              void* d_out, int out_size, void* d_ws, size_t ws_size,
                              hipStream_t stream) {
    const float* x = (const float*)d_in[0];
    float* out = (float*)d_out;

    float* scores = (float*)d_ws;                                   // BB*CC floats
    int* idx = (int*)((char*)d_ws + BB * CC * sizeof(float));       // BB*KK ints
    float* w = (float*)((char*)d_ws + BB * CC * sizeof(float) +
                        BB * KK * sizeof(int));                     // BB*KK floats

    scores_kernel<<<BB * CC, 256, 0, stream>>>(x, scores);
    topk_kernel<<<BB, CC, 0, stream>>>(scores, idx, w);
    gather_kernel<<<BB * KK, 256, 0, stream>>>(x, idx, w, out);
}

// Round 6
// 270.126 us; speedup vs baseline: 4.0309x; 1.0707x over previous
//
#include <hip/hip_runtime.h>

#define BB 32
#define CC 512
#define KK 128
#define HW 16384  // 128*128

typedef float f32x4 __attribute__((ext_vector_type(4)));

// ---------------------------------------------------------------------------
// Pass 1: per-(b,c) channel abs-max. One 256-thread block per channel.
// Nontemporal loads (validated win R1->R2; removal cost 20 us in R4).
// Score written with an AGENT-scope atomic store: performed at the cross-XCD
// coherence point, so visibility to pass 2 does not depend on kernel-boundary
// cache maintenance (which R5's post-timing failure suggests is weaker under
// graph replay than for fresh dispatches).
// ---------------------------------------------------------------------------
__global__ __launch_bounds__(256) void scores_kernel(const float* __restrict__ x,
                                                     float* __restrict__ scores) {
    const int ch = blockIdx.x;  // b*CC + c
    const f32x4* p = reinterpret_cast<const f32x4*>(x) + (size_t)ch * (HW / 4);
    const int tid = threadIdx.x;

    float m = 0.0f;
#pragma unroll
    for (int i = 0; i < 16; ++i) {
        f32x4 v = __builtin_nontemporal_load(&p[tid + i * 256]);
        m = fmaxf(m, fmaxf(fmaxf(fabsf(v.x), fabsf(v.y)),
                           fmaxf(fabsf(v.z), fabsf(v.w))));
    }
    // wave (64-lane) reduction
#pragma unroll
    for (int off = 32; off > 0; off >>= 1)
        m = fmaxf(m, __shfl_down(m, off, 64));

    __shared__ float smax[4];
    const int wave = tid >> 6;
    if ((tid & 63) == 0) smax[wave] = m;
    __syncthreads();
    if (tid == 0) {
        const float bm = fmaxf(fmaxf(smax[0], smax[1]), fmaxf(smax[2], smax[3]));
        __hip_atomic_store(&scores[ch], bm, __ATOMIC_RELAXED,
                           __HIP_MEMORY_SCOPE_AGENT);
    }
}

// ---------------------------------------------------------------------------
// Pass 2 (fused): each (b,k) block sorts its batch's 512 scores (bitonic,
// 256 thr x 2 elem — network validated in R3), derives its own channel index
// + softmax weight, then streams the channel. Scores are read with AGENT-
// scope atomic loads (coherence-point reads, the R3-proven path) — 8 MB total
// across all blocks, hidden under the 537 MB stream.
// ---------------------------------------------------------------------------
__global__ __launch_bounds__(256) void gather_topk_kernel(
        const float* __restrict__ x,
        const float* __restrict__ scores,
        float* __restrict__ out) {
    const int bk = blockIdx.x;   // b*KK + k
    const int b = bk >> 7;
    const int k = bk & (KK - 1);
    const int tid = threadIdx.x;

    __shared__ float s[CC];
    __shared__ int   idx[CC];
    __shared__ float red[2];

#pragma unroll
    for (int h = 0; h < 2; ++h) {
        const int c = tid + h * 256;
        s[c] = __hip_atomic_load(&scores[b * CC + c], __ATOMIC_RELAXED,
                                 __HIP_MEMORY_SCOPE_AGENT);
        idx[c] = c;
    }
    __syncthreads();

    // bitonic sort: descending by score, ties -> ascending index (lax.top_k)
    for (int kk = 2; kk <= CC; kk <<= 1) {
        for (int j = kk >> 1; j > 0; j >>= 1) {
            const int i   = 2 * tid - (tid & (j - 1));
            const int ixj = i + j;
            float sa = s[i], sb = s[ixj];
            int   ia = idx[i], ib = idx[ixj];
            const bool a_first  = (sa > sb) || (sa == sb && ia < ib);
            const bool desc_seg = ((i & kk) == 0);
            if (desc_seg ? !a_first : a_first) {
                s[i] = sb;  s[ixj] = sa;
                idx[i] = ib; idx[ixj] = ia;
            }
            __syncthreads();
        }
    }

    // softmax weight over top-K (Z cancels under normalization)
    const float smaxv = s[0];
    if (tid < KK) {
        float esum = expf(s[tid] - smaxv);
#pragma unroll
        for (int off = 32; off > 0; off >>= 1)
            esum += __shfl_down(esum, off, 64);
        if ((tid & 63) == 0) red[tid >> 6] = esum;
    }
    __syncthreads();
    const float total = fmaxf(red[0] + red[1], 1e-12f);
    const float wv = expf(s[k] - smaxv) / total;   // uniform across block
    const int   c  = idx[k];

    // ---- streaming copy: register-staged loads, nontemporal stores ----
    const f32x4* src = reinterpret_cast<const f32x4*>(x) +
                       ((size_t)(b * CC + c)) * (HW / 4);
    f32x4* dst = reinterpret_cast<f32x4*>(out) + (size_t)bk * (HW / 4);

    f32x4 r[16];
#pragma unroll
    for (int i = 0; i < 16; ++i)
        r[i] = src[tid + i * 256];
#pragma unroll
    for (int i = 0; i < 16; ++i) {
        f32x4 v = r[i];
        v.x *= wv; v.y *= wv; v.z *= wv; v.w *= wv;
        __builtin_nontemporal_store(v, &dst[tid + i * 256]);
    }
}

extern "C" void kernel_launch(void* const* d_in, const int* in_sizes, int n_in,
                              void* d_out, int out_size, void* d_ws, size_t ws_size,
                              hipStream_t stream) {
    const float* x = (const float*)d_in[0];
    float* out = (float*)d_out;
    float* scores = (float*)d_ws;  // BB*CC floats

    scores_kernel<<<BB * CC, 256, 0, stream>>>(x, scores);
    gather_topk_kernel<<<BB * KK, 256, 0, stream>>>(x, scores, out);
}